// Round 10
// baseline (159.394 us; speedup 1.0000x reference)
//
#include <hip/hip_runtime.h>

#define Bn 256
#define Nn 64
#define Tn 50
#define Fn 2
#define En 64
#define Hn 128
#define Rn 30
#define G4 512

typedef _Float16 h2    __attribute__((ext_vector_type(2)));
typedef _Float16 f16x8 __attribute__((ext_vector_type(8)));
typedef float    f32x4 __attribute__((ext_vector_type(4)));

__device__ __forceinline__ float sigf(float x) {
    return __builtin_amdgcn_rcpf(1.0f + __expf(-x));
}
__device__ __forceinline__ float tanh_fast(float x) {
    return 1.0f - 2.0f * __builtin_amdgcn_rcpf(__expf(2.0f * x) + 1.0f);
}
__device__ __forceinline__ float dot2(h2 a, h2 b, float c) {
#if __has_builtin(__builtin_amdgcn_fdot2)
    return __builtin_amdgcn_fdot2(a, b, c, false);
#else
    return fmaf((float)a[0], (float)b[0], fmaf((float)a[1], (float)b[1], c));
#endif
}
__device__ __forceinline__ h2 pack2(float a, float b) {
    h2 r; r[0] = (_Float16)a; r[1] = (_Float16)b; return r;
}
__device__ __forceinline__ h2 bch2(float u)        { return __builtin_bit_cast(h2, u); }
__device__ __forceinline__ h2 bchu(unsigned int u) { return __builtin_bit_cast(h2, u); }

// Raw workgroup barrier: LDS visibility (lgkmcnt) WITHOUT the vmcnt(0) drain
// that __syncthreads() emits — keeps XI prefetch loads in flight across steps.
__device__ __forceinline__ void blockbar() {
    __builtin_amdgcn_sched_barrier(0);
    asm volatile("s_waitcnt lgkmcnt(0)" ::: "memory");
    __builtin_amdgcn_s_barrier();
    __builtin_amdgcn_sched_barrier(0);
}

// ---------------- k_pre: GCN+emb (node 0) fused with XI = emb @ W_ih_e + b_e ----------------
// XI layout: XI[task][c*4+g] so k_seq reads 4 gate biases as one dwordx2.
__global__ __launch_bounds__(512) void k_pre(const float* __restrict__ src,
                                             const float* __restrict__ W_res,
                                             const float* __restrict__ W_gcn,
                                             const float* __restrict__ b_gcn,
                                             const float* __restrict__ W_ih_e,
                                             const float* __restrict__ b_e,
                                             _Float16* __restrict__ XI)
{
    const int tid  = threadIdx.x;
    const int lane = tid & 63;
    const int wv   = tid >> 6;
    const int task0 = blockIdx.x * 64;

    __shared__ __align__(16) _Float16 elds[64][64];
    __shared__ float2 xs[8][Nn];

    const float wg0 = W_gcn[lane], wg1 = W_gcn[En + lane];
    const float wr0 = W_res[lane], wr1 = W_res[En + lane];
    const float bg  = b_gcn[lane];

    for (int it = 0; it < 8; it++) {
        const int task = task0 + (wv << 3) + it;
        const int b = task / Tn;
        const int t = task - b * Tn;

        const float2 xv = *reinterpret_cast<const float2*>(
            src + (((size_t)b * Nn + lane) * Tn + t) * Fn);
        const float x0 = xv.x, x1 = xv.y;
        xs[wv][lane] = xv;

        float rowsum = 0.0f, w0 = 0.0f;
        #pragma unroll
        for (int k = 0; k < Nn; k++) {
            const float2 o = xs[wv][k];
            const float dx = x0 - o.x, dy = x1 - o.y;
            const float w = fminf(__builtin_amdgcn_rsqf(dx * dx + dy * dy), 1.0f);
            rowsum += w;
            if (k == 0) w0 = w;
        }
        const float dinv  = __builtin_amdgcn_rsqf(rowsum);
        const float dinv0 = __shfl(dinv, 0);
        const float a = w0 * dinv0 * dinv;

        float p0 = a * x0, p1 = a * x1;
        #pragma unroll
        for (int off = 32; off; off >>= 1) {
            p0 += __shfl_xor(p0, off);
            p1 += __shfl_xor(p1, off);
        }
        const float xa = __shfl(x0, 0);
        const float xb = __shfl(x1, 0);

        const float v = p0 * wg0 + p1 * wg1 + bg + xa * wr0 + xb * wr1;
        elds[(wv << 3) + it][lane] = (_Float16)fmaxf(v, 0.0f);
    }

    const int colp = (tid & 3) * 128 + (tid >> 2);
    h2 wih[32];
    #pragma unroll
    for (int q = 0; q < 32; q++)
        wih[q] = pack2(W_ih_e[(size_t)(2 * q) * G4 + colp],
                       W_ih_e[(size_t)(2 * q + 1) * G4 + colp]);
    const float be = b_e[colp];
    __syncthreads();

    for (int it = 0; it < 64; it++) {
        const float4* e4 = reinterpret_cast<const float4*>(&elds[it][0]);
        float acc = be;
        #pragma unroll
        for (int q = 0; q < 8; q++) {
            const float4 u = e4[q];
            acc = dot2(wih[4 * q + 0], bch2(u.x), acc);
            acc = dot2(wih[4 * q + 1], bch2(u.y), acc);
            acc = dot2(wih[4 * q + 2], bch2(u.z), acc);
            acc = dot2(wih[4 * q + 3], bch2(u.w), acc);
        }
        XI[(size_t)(task0 + it) * G4 + tid] = (_Float16)acc;
    }
}

// ---------------- k_seq: MFMA LSTM, counted-wait barriers, dist-2 XI prefetch ----------------
__global__ __launch_bounds__(512) void k_seq(
    const _Float16* __restrict__ XI,
    const float* __restrict__ src,
    const float* __restrict__ W_hh_e,
    const float* __restrict__ W1,     const float* __restrict__ b1,
    const float* __restrict__ W_ih_d, const float* __restrict__ W_hh_d,
    const float* __restrict__ b_d,
    const float* __restrict__ W2,     const float* __restrict__ b2,
    float* __restrict__ out)
{
    const int tid  = threadIdx.x;
    const int lane = tid & 63;
    const int wv   = tid >> 6;          // 0..7
    const int l15  = lane & 15;
    const int lg   = lane >> 4;         // 0..3
    const int cc   = wv * 16 + l15;     // cell column 0..127
    const int bq0  = blockIdx.x * 16;

    __shared__ __align__(16) _Float16 h_lds[2][16 * 128];
    __shared__ __align__(16) _Float16 ed_lds[2][16 * 64];
    __shared__ __align__(16) _Float16 wi_frag[8 * 8 * 64 * 8];
    __shared__ __align__(16) float    redw[8][4][8];

    // ---- encoder W_hh fragments (64 VGPR) ----
    f16x8 bfr[4][4];
    #pragma unroll
    for (int g = 0; g < 4; g++)
        #pragma unroll
        for (int kt = 0; kt < 4; kt++) {
            f16x8 v;
            #pragma unroll
            for (int j = 0; j < 8; j++)
                v[j] = (_Float16)W_hh_e[(size_t)(kt * 32 + lg * 8 + j) * G4 + g * 128 + cc];
            bfr[g][kt] = v;
        }

    #pragma unroll
    for (int q = 0; q < 2; q++)
        reinterpret_cast<float*>(&h_lds[0][0])[tid + q * 512] = 0.0f;

    f32x4 cst = {};
    char* const hb0 = reinterpret_cast<char*>(&h_lds[0][0]);
    char* const hb1 = reinterpret_cast<char*>(&h_lds[1][0]);
    const _Float16* const XIbase = XI + (size_t)bq0 * Tn * G4 + cc * 4;

    // XI prologue loads (t=0, t=1)
    uint2 xi0[4], xi1[4];
    #pragma unroll
    for (int i = 0; i < 4; i++) {
        xi0[i] = *reinterpret_cast<const uint2*>(XIbase + ((size_t)(4 * lg + i) * Tn + 0) * G4);
        xi1[i] = *reinterpret_cast<const uint2*>(XIbase + ((size_t)(4 * lg + i) * Tn + 1) * G4);
    }
    __syncthreads();

    // ---- encoder: 50 steps (unroll 2), 1 raw barrier/step ----
    for (int t = 0; t < Tn; t += 2) {
        // prefetch t+2 / t+3 (distance 2; consumed next unrolled iteration)
        uint2 nxt0[4], nxt1[4];
        const int t2 = (t + 2 < Tn) ? t + 2 : t;
        const int t3 = (t + 3 < Tn) ? t + 3 : t;
        #pragma unroll
        for (int i = 0; i < 4; i++) {
            nxt0[i] = *reinterpret_cast<const uint2*>(XIbase + ((size_t)(4 * lg + i) * Tn + t2) * G4);
            nxt1[i] = *reinterpret_cast<const uint2*>(XIbase + ((size_t)(4 * lg + i) * Tn + t3) * G4);
        }

        #pragma unroll
        for (int half = 0; half < 2; half++) {
            char* const hr = half ? hb1 : hb0;
            char* const hw = half ? hb0 : hb1;
            const uint2* xiv = half ? xi1 : xi0;

            f16x8 af[4];
            #pragma unroll
            for (int kt = 0; kt < 4; kt++) {
                const int abyte = (l15 * 256 + kt * 64 + lg * 16) ^ ((l15 & 7) << 4);
                af[kt] = *reinterpret_cast<const f16x8*>(hr + abyte);
            }

            f32x4 acc[4] = {};
            #pragma unroll
            for (int kt = 0; kt < 4; kt++)
                #pragma unroll
                for (int g = 0; g < 4; g++)
                    acc[g] = __builtin_amdgcn_mfma_f32_16x16x32_f16(af[kt], bfr[g][kt], acc[g], 0, 0, 0);

            #pragma unroll
            for (int i = 0; i < 4; i++) {
                const h2 lo = bchu(xiv[i].x);
                const h2 hi = bchu(xiv[i].y);
                const float gi = acc[0][i] + (float)lo[0];
                const float gf = acc[1][i] + (float)lo[1];
                const float gg = acc[2][i] + (float)hi[0];
                const float go = acc[3][i] + (float)hi[1];
                cst[i] = sigf(gf) * cst[i] + sigf(gi) * tanh_fast(gg);
                const float hv = sigf(go) * tanh_fast(cst[i]);
                const int m = 4 * lg + i;
                const int hbyte = (m * 256 + cc * 2) ^ ((m & 7) << 4);
                *reinterpret_cast<_Float16*>(hw + hbyte) = (_Float16)hv;
            }
            blockbar();
        }

        #pragma unroll
        for (int i = 0; i < 4; i++) { xi0[i] = nxt0[i]; xi1[i] = nxt1[i]; }
    }

    // ---- decoder setup ----
    #pragma unroll
    for (int g = 0; g < 4; g++)
        #pragma unroll
        for (int kt = 0; kt < 4; kt++) {
            f16x8 v;
            #pragma unroll
            for (int j = 0; j < 8; j++)
                v[j] = (_Float16)W_hh_d[(size_t)(kt * 32 + lg * 8 + j) * G4 + g * 128 + cc];
            bfr[g][kt] = v;
        }
    #pragma unroll
    for (int g = 0; g < 4; g++)
        #pragma unroll
        for (int kt2 = 0; kt2 < 2; kt2++) {
            f16x8 v;
            #pragma unroll
            for (int j = 0; j < 8; j++)
                v[j] = (_Float16)W_ih_d[(size_t)(kt2 * 32 + lg * 8 + j) * G4 + g * 128 + cc];
            *reinterpret_cast<f16x8*>(&wi_frag[((wv * 8 + g * 2 + kt2) * 64 + lane) * 8]) = v;
        }

    const float bd0 = b_d[cc], bd1 = b_d[128 + cc], bd2 = b_d[256 + cc], bd3 = b_d[384 + cc];
    const float w2a = W2[cc * 2], w2b = W2[cc * 2 + 1];
    const int   e   = tid & 63;
    const int   mh  = wv;
    const float w1a = W1[e], w1b = W1[En + e], b1v = b1[e];
    const float b20 = b2[0], b21 = b2[1];

    char* const eb0 = reinterpret_cast<char*>(&ed_lds[0][0]);
    char* const eb1 = reinterpret_cast<char*>(&ed_lds[1][0]);

    #pragma unroll
    for (int q = 0; q < 2; q++) {
        const int m = mh + 8 * q;
        const float xin0 = src[((size_t)(bq0 + m) * Nn * Tn + (Tn - 1)) * Fn + 0];
        const float xin1 = src[((size_t)(bq0 + m) * Nn * Tn + (Tn - 1)) * Fn + 1];
        const float ed = fmaxf(xin0 * w1a + xin1 * w1b + b1v, 0.0f);
        const int ebyte = (m * 128 + e * 2) ^ ((m & 7) << 4);
        *reinterpret_cast<_Float16*>(eb0 + ebyte) = (_Float16)ed;
    }
    __syncthreads();

    // ---- decoder: 30 steps, 2 raw barriers/step ----
    for (int r = 0; r < Rn; r++) {
        const int cur = r & 1;
        char* const hr = cur ? hb1 : hb0;
        char* const hw = cur ? hb0 : hb1;
        char* const er = cur ? eb1 : eb0;
        char* const ew = cur ? eb0 : eb1;

        f16x8 af[4];
        #pragma unroll
        for (int kt = 0; kt < 4; kt++) {
            const int abyte = (l15 * 256 + kt * 64 + lg * 16) ^ ((l15 & 7) << 4);
            af[kt] = *reinterpret_cast<const f16x8*>(hr + abyte);
        }
        f16x8 ae[2];
        #pragma unroll
        for (int kt2 = 0; kt2 < 2; kt2++) {
            const int aebyte = (l15 * 128 + kt2 * 64 + lg * 16) ^ ((l15 & 7) << 4);
            ae[kt2] = *reinterpret_cast<const f16x8*>(er + aebyte);
        }

        f32x4 acc[4] = {};
        #pragma unroll
        for (int kt = 0; kt < 4; kt++)
            #pragma unroll
            for (int g = 0; g < 4; g++)
                acc[g] = __builtin_amdgcn_mfma_f32_16x16x32_f16(af[kt], bfr[g][kt], acc[g], 0, 0, 0);
        #pragma unroll
        for (int g = 0; g < 4; g++)
            #pragma unroll
            for (int kt2 = 0; kt2 < 2; kt2++) {
                const f16x8 bfe = *reinterpret_cast<const f16x8*>(
                    &wi_frag[((wv * 8 + g * 2 + kt2) * 64 + lane) * 8]);
                acc[g] = __builtin_amdgcn_mfma_f32_16x16x32_f16(ae[kt2], bfe, acc[g], 0, 0, 0);
            }

        float hv4[4];
        #pragma unroll
        for (int i = 0; i < 4; i++) {
            const float gi = acc[0][i] + bd0;
            const float gf = acc[1][i] + bd1;
            const float gg = acc[2][i] + bd2;
            const float go = acc[3][i] + bd3;
            cst[i] = sigf(gf) * cst[i] + sigf(gi) * tanh_fast(gg);
            const float hv = sigf(go) * tanh_fast(cst[i]);
            hv4[i] = hv;
            const int m = 4 * lg + i;
            const int hbyte = (m * 256 + cc * 2) ^ ((m & 7) << 4);
            *reinterpret_cast<_Float16*>(hw + hbyte) = (_Float16)hv;
        }

        float p[8];
        #pragma unroll
        for (int i = 0; i < 4; i++) { p[2 * i] = hv4[i] * w2a; p[2 * i + 1] = hv4[i] * w2b; }
        #pragma unroll
        for (int off = 1; off < 16; off <<= 1)
            #pragma unroll
            for (int v = 0; v < 8; v++) p[v] += __shfl_xor(p[v], off);
        if (l15 == 0) {
            *reinterpret_cast<float4*>(&redw[wv][lg][0]) = make_float4(p[0], p[1], p[2], p[3]);
            *reinterpret_cast<float4*>(&redw[wv][lg][4]) = make_float4(p[4], p[5], p[6], p[7]);
        }
        blockbar();

        #pragma unroll
        for (int q = 0; q < 2; q++) {
            const int m = mh + 8 * q;
            const int lgq = m >> 2, iq = m & 3;
            float o0 = b20, o1 = b21;
            #pragma unroll
            for (int w8 = 0; w8 < 8; w8++) {
                o0 += redw[w8][lgq][iq * 2];
                o1 += redw[w8][lgq][iq * 2 + 1];
            }
            if (e < 2)
                out[(((size_t)(bq0 + m)) * Rn + r) * Fn + e] = e ? o1 : o0;
            if (r + 1 < Rn) {
                const float ed = fmaxf(o0 * w1a + o1 * w1b + b1v, 0.0f);
                const int ebyte = (m * 128 + e * 2) ^ ((m & 7) << 4);
                *reinterpret_cast<_Float16*>(ew + ebyte) = (_Float16)ed;
            }
        }
        blockbar();
    }
}

extern "C" void kernel_launch(void* const* d_in, const int* in_sizes, int n_in,
                              void* d_out, int out_size, void* d_ws, size_t ws_size,
                              hipStream_t stream)
{
    const float* src    = (const float*)d_in[0];
    const float* W_res  = (const float*)d_in[2];
    const float* W_gcn  = (const float*)d_in[3];
    const float* b_gcn  = (const float*)d_in[4];
    const float* W_ih_e = (const float*)d_in[5];
    const float* W_hh_e = (const float*)d_in[6];
    const float* b_e    = (const float*)d_in[7];
    const float* W1     = (const float*)d_in[8];
    const float* b1     = (const float*)d_in[9];
    const float* W_ih_d = (const float*)d_in[10];
    const float* W_hh_d = (const float*)d_in[11];
    const float* b_d    = (const float*)d_in[12];
    const float* W2     = (const float*)d_in[13];
    const float* b2     = (const float*)d_in[14];

    float* out = (float*)d_out;
    _Float16* XI = (_Float16*)d_ws;   // 12800 x 512 fp16 = 13.1 MB scratch

    k_pre<<<(Bn * Tn) / 64, 512, 0, stream>>>(src, W_res, W_gcn, b_gcn, W_ih_e, b_e, XI);
    k_seq<<<Bn / 16, 512, 0, stream>>>(XI, src,
                                       W_hh_e,
                                       W1, b1,
                                       W_ih_d, W_hh_d, b_d,
                                       W2, b2, out);
}

// Round 11
// 102.617 us; speedup vs baseline: 1.5533x; 1.5533x over previous
//
#include <hip/hip_runtime.h>

#define Bn 256
#define Nn 64
#define Tn 50
#define Fn 2
#define En 64
#define Hn 128
#define Rn 30
#define G4 512

typedef _Float16 h2    __attribute__((ext_vector_type(2)));
typedef _Float16 f16x8 __attribute__((ext_vector_type(8)));
typedef float    f32x4 __attribute__((ext_vector_type(4)));

__device__ __forceinline__ float sigf(float x) {
    return __builtin_amdgcn_rcpf(1.0f + __expf(-x));
}
__device__ __forceinline__ float tanh_fast(float x) {
    return 1.0f - 2.0f * __builtin_amdgcn_rcpf(__expf(2.0f * x) + 1.0f);
}
__device__ __forceinline__ float dot2(h2 a, h2 b, float c) {
#if __has_builtin(__builtin_amdgcn_fdot2)
    return __builtin_amdgcn_fdot2(a, b, c, false);
#else
    return fmaf((float)a[0], (float)b[0], fmaf((float)a[1], (float)b[1], c));
#endif
}
__device__ __forceinline__ h2 pack2(float a, float b) {
    h2 r; r[0] = (_Float16)a; r[1] = (_Float16)b; return r;
}
__device__ __forceinline__ h2 bch2(float u)        { return __builtin_bit_cast(h2, u); }
__device__ __forceinline__ h2 bchu(unsigned int u) { return __builtin_bit_cast(h2, u); }

// lgkm-only barrier (no vmcnt drain)
__device__ __forceinline__ void blockbar() {
    __builtin_amdgcn_sched_barrier(0);
    asm volatile("s_waitcnt lgkmcnt(0)" ::: "memory");
    __builtin_amdgcn_s_barrier();
    __builtin_amdgcn_sched_barrier(0);
}

// ---------------- k_pre: GCN+emb (node 0) fused with XI = emb @ W_ih_e + b_e ----------------
// XI layout: XI[task][c*4+g] (verified R9/R10).
__global__ __launch_bounds__(512) void k_pre(const float* __restrict__ src,
                                             const float* __restrict__ W_res,
                                             const float* __restrict__ W_gcn,
                                             const float* __restrict__ b_gcn,
                                             const float* __restrict__ W_ih_e,
                                             const float* __restrict__ b_e,
                                             _Float16* __restrict__ XI)
{
    const int tid  = threadIdx.x;
    const int lane = tid & 63;
    const int wv   = tid >> 6;
    const int task0 = blockIdx.x * 64;

    __shared__ __align__(16) _Float16 elds[64][64];
    __shared__ float2 xs[8][Nn];

    const float wg0 = W_gcn[lane], wg1 = W_gcn[En + lane];
    const float wr0 = W_res[lane], wr1 = W_res[En + lane];
    const float bg  = b_gcn[lane];

    for (int it = 0; it < 8; it++) {
        const int task = task0 + (wv << 3) + it;
        const int b = task / Tn;
        const int t = task - b * Tn;

        const float2 xv = *reinterpret_cast<const float2*>(
            src + (((size_t)b * Nn + lane) * Tn + t) * Fn);
        const float x0 = xv.x, x1 = xv.y;
        xs[wv][lane] = xv;

        float rowsum = 0.0f, w0 = 0.0f;
        #pragma unroll
        for (int k = 0; k < Nn; k++) {
            const float2 o = xs[wv][k];
            const float dx = x0 - o.x, dy = x1 - o.y;
            const float w = fminf(__builtin_amdgcn_rsqf(dx * dx + dy * dy), 1.0f);
            rowsum += w;
            if (k == 0) w0 = w;
        }
        const float dinv  = __builtin_amdgcn_rsqf(rowsum);
        const float dinv0 = __shfl(dinv, 0);
        const float a = w0 * dinv0 * dinv;

        float p0 = a * x0, p1 = a * x1;
        #pragma unroll
        for (int off = 32; off; off >>= 1) {
            p0 += __shfl_xor(p0, off);
            p1 += __shfl_xor(p1, off);
        }
        const float xa = __shfl(x0, 0);
        const float xb = __shfl(x1, 0);

        const float v = p0 * wg0 + p1 * wg1 + bg + xa * wr0 + xb * wr1;
        elds[(wv << 3) + it][lane] = (_Float16)fmaxf(v, 0.0f);
    }

    const int colp = (tid & 3) * 128 + (tid >> 2);
    h2 wih[32];
    #pragma unroll
    for (int q = 0; q < 32; q++)
        wih[q] = pack2(W_ih_e[(size_t)(2 * q) * G4 + colp],
                       W_ih_e[(size_t)(2 * q + 1) * G4 + colp]);
    const float be = b_e[colp];
    __syncthreads();

    for (int it = 0; it < 64; it++) {
        const float4* e4 = reinterpret_cast<const float4*>(&elds[it][0]);
        float acc = be;
        #pragma unroll
        for (int q = 0; q < 8; q++) {
            const float4 u = e4[q];
            acc = dot2(wih[4 * q + 0], bch2(u.x), acc);
            acc = dot2(wih[4 * q + 1], bch2(u.y), acc);
            acc = dot2(wih[4 * q + 2], bch2(u.z), acc);
            acc = dot2(wih[4 * q + 3], bch2(u.w), acc);
        }
        XI[(size_t)(task0 + it) * G4 + tid] = (_Float16)acc;
    }
}

// ---------------- k_seq: M=4 replicated-A MFMA LSTM, 1 cell/thread ----------------
// 64 blocks x 512 thr; block owns 4 batches. A rows replicated (A[r]=h[r&3])
// so D rows 4lg+i hold batch i in EVERY quarter: lane (l15,lg) selects
// acc[g][lg] (cndmask, no shuffle) and owns cell (m=lg, c=16wv+l15).
// Gate phase: 1 cell/thread -> 4x less trans issue than R10. h_lds: 4 rows,
// 288B stride (bank-spread); A-reads broadcast 4 lanes/addr (free).
__global__ __launch_bounds__(512) void k_seq(
    const _Float16* __restrict__ XI,
    const float* __restrict__ src,
    const float* __restrict__ W_hh_e,
    const float* __restrict__ W1,     const float* __restrict__ b1,
    const float* __restrict__ W_ih_d, const float* __restrict__ W_hh_d,
    const float* __restrict__ b_d,
    const float* __restrict__ W2,     const float* __restrict__ b2,
    float* __restrict__ out)
{
    const int tid  = threadIdx.x;
    const int lane = tid & 63;
    const int wv   = tid >> 6;          // 0..7
    const int l15  = lane & 15;
    const int lg   = lane >> 4;         // 0..3 : k-subgroup AND owned batch m
    const int cc   = wv * 16 + l15;     // owned cell column 0..127
    const int bq0  = blockIdx.x * 4;    // 4 batches per block

    // h: 4 rows x 128 c fp16, row stride 288 B (=144 halves) for bank spread
    __shared__ __align__(16) _Float16 hbuf[2][576];
    // ed: 4 rows x 64 c fp16, row stride 160 B (=80 halves)
    __shared__ __align__(16) _Float16 edbuf[2][320];
    __shared__ __align__(16) _Float16 wi_frag[8 * 8 * 64 * 8];   // 64 KB
    __shared__ __align__(16) float    redw[8][4][2];

    // ---- encoder W_hh B-fragments (verified layout) ----
    f16x8 bfr[4][4];   // [gate][kt]: lane j holds W[kt*32+lg*8+j][g*128+cc]
    #pragma unroll
    for (int g = 0; g < 4; g++)
        #pragma unroll
        for (int kt = 0; kt < 4; kt++) {
            f16x8 v;
            #pragma unroll
            for (int j = 0; j < 8; j++)
                v[j] = (_Float16)W_hh_e[(size_t)(kt * 32 + lg * 8 + j) * G4 + g * 128 + cc];
            bfr[g][kt] = v;
        }

    // zero h buffer 0 (576 halves = 288 dwords)
    if (tid < 288) reinterpret_cast<float*>(&hbuf[0][0])[tid] = 0.0f;

    float cst = 0.0f;
    char* const hb0 = reinterpret_cast<char*>(&hbuf[0][0]);
    char* const hb1 = reinterpret_cast<char*>(&hbuf[1][0]);
    const _Float16* const XIrow = XI + (size_t)(bq0 + lg) * Tn * G4 + cc * 4;

    uint2 xi0, xi1;
    xi0 = *reinterpret_cast<const uint2*>(XIrow + 0 * G4);
    xi1 = *reinterpret_cast<const uint2*>(XIrow + 1 * G4);
    __syncthreads();

    // ---- encoder: 50 steps (unroll 2), 1 barrier/step ----
    for (int t = 0; t < Tn; t += 2) {
        uint2 nxt0, nxt1;
        const int t2 = (t + 2 < Tn) ? t + 2 : t;
        const int t3 = (t + 3 < Tn) ? t + 3 : t;
        nxt0 = *reinterpret_cast<const uint2*>(XIrow + (size_t)t2 * G4);
        nxt1 = *reinterpret_cast<const uint2*>(XIrow + (size_t)t3 * G4);

        #pragma unroll
        for (int half = 0; half < 2; half++) {
            char* const hr = half ? hb1 : hb0;
            char* const hw = half ? hb0 : hb1;
            const uint2 xiv = half ? xi1 : xi0;

            // A fragments: row r = l15&3 (replication), 4 lanes/addr broadcast
            f16x8 af[4];
            #pragma unroll
            for (int kt = 0; kt < 4; kt++)
                af[kt] = *reinterpret_cast<const f16x8*>(
                    hr + (l15 & 3) * 288 + kt * 64 + lg * 16);

            f32x4 acc[4] = {};
            #pragma unroll
            for (int kt = 0; kt < 4; kt++)
                #pragma unroll
                for (int g = 0; g < 4; g++)
                    acc[g] = __builtin_amdgcn_mfma_f32_16x16x32_f16(af[kt], bfr[g][kt], acc[g], 0, 0, 0);

            // select batch lg from the replicated D rows (constant-index ternaries)
            float ga[4];
            #pragma unroll
            for (int g = 0; g < 4; g++) {
                const float s01 = (lg & 1) ? acc[g][1] : acc[g][0];
                const float s23 = (lg & 1) ? acc[g][3] : acc[g][2];
                ga[g] = (lg & 2) ? s23 : s01;
            }

            const h2 lo = bchu(xiv.x);
            const h2 hi = bchu(xiv.y);
            const float gi = ga[0] + (float)lo[0];
            const float gf = ga[1] + (float)lo[1];
            const float gg = ga[2] + (float)hi[0];
            const float go = ga[3] + (float)hi[1];
            cst = sigf(gf) * cst + sigf(gi) * tanh_fast(gg);
            const float hv = sigf(go) * tanh_fast(cst);

            *reinterpret_cast<_Float16*>(hw + lg * 288 + cc * 2) = (_Float16)hv;
            blockbar();
        }
        xi0 = nxt0; xi1 = nxt1;
    }

    // ---- decoder setup ----
    #pragma unroll
    for (int g = 0; g < 4; g++)
        #pragma unroll
        for (int kt = 0; kt < 4; kt++) {
            f16x8 v;
            #pragma unroll
            for (int j = 0; j < 8; j++)
                v[j] = (_Float16)W_hh_d[(size_t)(kt * 32 + lg * 8 + j) * G4 + g * 128 + cc];
            bfr[g][kt] = v;
        }
    #pragma unroll
    for (int g = 0; g < 4; g++)
        #pragma unroll
        for (int kt2 = 0; kt2 < 2; kt2++) {
            f16x8 v;
            #pragma unroll
            for (int j = 0; j < 8; j++)
                v[j] = (_Float16)W_ih_d[(size_t)(kt2 * 32 + lg * 8 + j) * G4 + g * 128 + cc];
            *reinterpret_cast<f16x8*>(&wi_frag[((wv * 8 + g * 2 + kt2) * 64 + lane) * 8]) = v;
        }

    const float bd0 = b_d[cc], bd1 = b_d[128 + cc], bd2 = b_d[256 + cc], bd3 = b_d[384 + cc];
    const float w2a = W2[cc * 2], w2b = W2[cc * 2 + 1];
    const int   e   = (wv & 3) * 16 + l15;   // ED column for producer threads (wv<4)
    const float w1a = W1[e], w1b = W1[En + e], b1v = b1[e];
    const float b20 = b2[0], b21 = b2[1];

    char* const eb0 = reinterpret_cast<char*>(&edbuf[0][0]);
    char* const eb1 = reinterpret_cast<char*>(&edbuf[1][0]);

    // ED init: producers wv<4 cover (m=lg, e); m's xin from src[b, node0, T-1]
    if (wv < 4) {
        const float xin0 = src[((size_t)(bq0 + lg) * Nn * Tn + (Tn - 1)) * Fn + 0];
        const float xin1 = src[((size_t)(bq0 + lg) * Nn * Tn + (Tn - 1)) * Fn + 1];
        const float ed = fmaxf(xin0 * w1a + xin1 * w1b + b1v, 0.0f);
        *reinterpret_cast<_Float16*>(eb0 + lg * 160 + e * 2) = (_Float16)ed;
    }
    __syncthreads();

    // ---- decoder: 30 steps, 2 barriers/step ----
    for (int r = 0; r < Rn; r++) {
        const int cur = r & 1;
        char* const hr = cur ? hb1 : hb0;
        char* const hw = cur ? hb0 : hb1;
        char* const er = cur ? eb1 : eb0;
        char* const ew = cur ? eb0 : eb1;

        f16x8 af[4];
        #pragma unroll
        for (int kt = 0; kt < 4; kt++)
            af[kt] = *reinterpret_cast<const f16x8*>(
                hr + (l15 & 3) * 288 + kt * 64 + lg * 16);
        f16x8 ae[2];
        #pragma unroll
        for (int kt2 = 0; kt2 < 2; kt2++)
            ae[kt2] = *reinterpret_cast<const f16x8*>(
                er + (l15 & 3) * 160 + kt2 * 64 + lg * 16);

        f32x4 acc[4] = {};
        #pragma unroll
        for (int kt = 0; kt < 4; kt++)
            #pragma unroll
            for (int g = 0; g < 4; g++)
                acc[g] = __builtin_amdgcn_mfma_f32_16x16x32_f16(af[kt], bfr[g][kt], acc[g], 0, 0, 0);
        #pragma unroll
        for (int g = 0; g < 4; g++)
            #pragma unroll
            for (int kt2 = 0; kt2 < 2; kt2++) {
                const f16x8 bfe = *reinterpret_cast<const f16x8*>(
                    &wi_frag[((wv * 8 + g * 2 + kt2) * 64 + lane) * 8]);
                acc[g] = __builtin_amdgcn_mfma_f32_16x16x32_f16(ae[kt2], bfe, acc[g], 0, 0, 0);
            }

        float ga[4];
        #pragma unroll
        for (int g = 0; g < 4; g++) {
            const float s01 = (lg & 1) ? acc[g][1] : acc[g][0];
            const float s23 = (lg & 1) ? acc[g][3] : acc[g][2];
            ga[g] = (lg & 2) ? s23 : s01;
        }

        const float gi = ga[0] + bd0;
        const float gf = ga[1] + bd1;
        const float gg = ga[2] + bd2;
        const float go = ga[3] + bd3;
        cst = sigf(gf) * cst + sigf(gi) * tanh_fast(gg);
        const float hv = sigf(go) * tanh_fast(cst);
        *reinterpret_cast<_Float16*>(hw + lg * 288 + cc * 2) = (_Float16)hv;

        // out-projection: butterfly over the 16 l15 lanes (quarter-local)
        float p0 = hv * w2a, p1 = hv * w2b;
        #pragma unroll
        for (int off = 1; off < 16; off <<= 1) {
            p0 += __shfl_xor(p0, off);
            p1 += __shfl_xor(p1, off);
        }
        if (l15 == 0) { redw[wv][lg][0] = p0; redw[wv][lg][1] = p1; }
        blockbar();

        // o for batch m=lg (broadcast reads), out-write, next ED
        float o0 = b20, o1 = b21;
        #pragma unroll
        for (int w8 = 0; w8 < 8; w8++) {
            o0 += redw[w8][lg][0];
            o1 += redw[w8][lg][1];
        }
        if (wv == 4 && l15 < 2)
            out[(((size_t)(bq0 + lg)) * Rn + r) * Fn + l15] = l15 ? o1 : o0;
        if (wv < 4 && r + 1 < Rn) {
            const float ed = fmaxf(o0 * w1a + o1 * w1b + b1v, 0.0f);
            *reinterpret_cast<_Float16*>(ew + lg * 160 + e * 2) = (_Float16)ed;
        }
        blockbar();
    }
}

extern "C" void kernel_launch(void* const* d_in, const int* in_sizes, int n_in,
                              void* d_out, int out_size, void* d_ws, size_t ws_size,
                              hipStream_t stream)
{
    const float* src    = (const float*)d_in[0];
    const float* W_res  = (const float*)d_in[2];
    const float* W_gcn  = (const float*)d_in[3];
    const float* b_gcn  = (const float*)d_in[4];
    const float* W_ih_e = (const float*)d_in[5];
    const float* W_hh_e = (const float*)d_in[6];
    const float* b_e    = (const float*)d_in[7];
    const float* W1     = (const float*)d_in[8];
    const float* b1     = (const float*)d_in[9];
    const float* W_ih_d = (const float*)d_in[10];
    const float* W_hh_d = (const float*)d_in[11];
    const float* b_d    = (const float*)d_in[12];
    const float* W2     = (const float*)d_in[13];
    const float* b2     = (const float*)d_in[14];

    float* out = (float*)d_out;
    _Float16* XI = (_Float16*)d_ws;   // 12800 x 512 fp16 = 13.1 MB scratch

    k_pre<<<(Bn * Tn) / 64, 512, 0, stream>>>(src, W_res, W_gcn, b_gcn, W_ih_e, b_e, XI);
    k_seq<<<Bn / 4, 512, 0, stream>>>(XI, src,
                                      W_hh_e,
                                      W1, b1,
                                      W_ih_d, W_hh_d, b_d,
                                      W2, b2, out);
}